// Round 1
// baseline (85.555 us; speedup 1.0000x reference)
//
#include <hip/hip_runtime.h>

// Problem constants (fixed by the reference setup_inputs()).
#define F_DIM   1024   // in_features
#define O_DIM   1024   // out_features
#define W_DIM   7      // DEGREE - START_DEGREE + 1
#define BLOCK   256

// One block per batch row b:
//   phase 1: 256 threads x float4 -> per-thread partial sums of the 7
//            gaussian-weighted Hermite basis values over the row's 1024 feats
//   phase 2: wave64 shuffle reduce + 4-wave LDS reduce -> basis[7]
//   phase 3: each thread writes 4 outputs out[b][o] = sum_w basis[w]*coeffs[o][w]
__global__ __launch_bounds__(BLOCK) void hermite_fused(
    const float* __restrict__ x,
    const float* __restrict__ coeffs,
    const float* __restrict__ sigma,
    float* __restrict__ out)
{
    __shared__ float s_coeffs[O_DIM * W_DIM];   // 28672 B
    __shared__ float s_partial[4][W_DIM];
    __shared__ float s_basis[W_DIM];

    const int tid = threadIdx.x;
    const int b   = blockIdx.x;

    // Stage coeffs into LDS (coalesced; 7 loads/thread).
    for (int i = tid; i < O_DIM * W_DIM; i += BLOCK)
        s_coeffs[i] = coeffs[i];

    const float s = fminf(fmaxf(sigma[0], 0.1f), 5.0f);

    // ---- phase 1: per-thread partial basis sums over 4 elements ----
    float acc[W_DIM];
#pragma unroll
    for (int w = 0; w < W_DIM; ++w) acc[w] = 0.0f;

    const float4 v = ((const float4*)(x + (size_t)b * F_DIM))[tid];
    const float elems[4] = {v.x, v.y, v.z, v.w};

#pragma unroll
    for (int e = 0; e < 4; ++e) {
        const float xs = elems[e] / s;
        const float g  = expf(-fminf(xs * xs, 50.0f));
        // Probabilists'-style recursion as written in the reference:
        // H0=1, H1=2x, Hn = 2x*H_{n-1} - 2(n-1)*H_{n-2}, clip Hn (n>=2)
        // to [-100,100] BEFORE it feeds the next step.
        float hm2 = 1.0f;
        float hm1 = 2.0f * xs;
        acc[0] += g;          // H0 * g
        acc[1] += hm1 * g;    // H1 * g (unclipped, matches ref)
#pragma unroll
        for (int n = 2; n <= 6; ++n) {
            float hn = 2.0f * xs * hm1 - 2.0f * (float)(n - 1) * hm2;
            hn = fminf(fmaxf(hn, -100.0f), 100.0f);
            acc[n] += hn * g;
            hm2 = hm1;
            hm1 = hn;
        }
    }

    // ---- phase 2: reduce 7 accumulators across the block ----
#pragma unroll
    for (int w = 0; w < W_DIM; ++w) {
        float a = acc[w];
#pragma unroll
        for (int off = 32; off > 0; off >>= 1)
            a += __shfl_down(a, off, 64);
        acc[w] = a;
    }
    const int wave = tid >> 6;
    const int lane = tid & 63;
    if (lane == 0) {
#pragma unroll
        for (int w = 0; w < W_DIM; ++w) s_partial[wave][w] = acc[w];
    }
    __syncthreads();
    if (tid < W_DIM) {
        s_basis[tid] = s_partial[0][tid] + s_partial[1][tid]
                     + s_partial[2][tid] + s_partial[3][tid];
    }
    __syncthreads();

    float basis[W_DIM];
#pragma unroll
    for (int w = 0; w < W_DIM; ++w) basis[w] = s_basis[w];

    // ---- phase 3: out[b][o] = sum_w basis[w] * coeffs[o][w] ----
    float* orow = out + (size_t)b * O_DIM;
#pragma unroll
    for (int k = 0; k < O_DIM / BLOCK; ++k) {
        const int o = tid + k * BLOCK;
        const float* c = &s_coeffs[o * W_DIM];
        float r = 0.0f;
#pragma unroll
        for (int w = 0; w < W_DIM; ++w) r += basis[w] * c[w];
        orow[o] = r;
    }
}

extern "C" void kernel_launch(void* const* d_in, const int* in_sizes, int n_in,
                              void* d_out, int out_size, void* d_ws, size_t ws_size,
                              hipStream_t stream) {
    const float* x      = (const float*)d_in[0];  // (B, F) fp32
    const float* coeffs = (const float*)d_in[1];  // (O, W) fp32
    const float* sigma  = (const float*)d_in[2];  // (1,)   fp32
    float* out          = (float*)d_out;          // (B, O) fp32

    const int B = in_sizes[0] / F_DIM;
    hermite_fused<<<dim3(B), dim3(BLOCK), 0, stream>>>(x, coeffs, sigma, out);
}

// Round 2
// 81.926 us; speedup vs baseline: 1.0443x; 1.0443x over previous
//
#include <hip/hip_runtime.h>

// Problem constants (fixed by the reference setup_inputs()).
#define F_DIM   1024   // in_features
#define O_DIM   1024   // out_features
#define W_DIM   7      // DEGREE - START_DEGREE + 1
#define BLOCK   256
#define RB      8      // rows per block in the output kernel

// ---------------------------------------------------------------------------
// K1: basis[b][w] = sum_f gaussian(xs) * H_w(xs),  xs = x[b][f]/s
// One block per batch row. Reads 16 MiB of x, writes B*7 floats to ws.
// ---------------------------------------------------------------------------
__global__ __launch_bounds__(BLOCK) void hermite_basis(
    const float* __restrict__ x,
    const float* __restrict__ sigma,
    float* __restrict__ basis)        // (B, W_DIM) in d_ws
{
    __shared__ float s_part[4][W_DIM + 1];

    const int tid = threadIdx.x;
    const int b   = blockIdx.x;

    const float s     = fminf(fmaxf(sigma[0], 0.1f), 5.0f);
    const float inv_s = 1.0f / s;   // one divide, hoisted out of the loop

    const float4 v = ((const float4*)(x + (size_t)b * F_DIM))[tid];
    const float elems[4] = {v.x, v.y, v.z, v.w};

    float acc[W_DIM];
#pragma unroll
    for (int w = 0; w < W_DIM; ++w) acc[w] = 0.0f;

#pragma unroll
    for (int e = 0; e < 4; ++e) {
        const float xs = elems[e] * inv_s;
        const float g  = __expf(-fminf(xs * xs, 50.0f));
        // H0=1, H1=2x, Hn = 2x*H_{n-1} - 2(n-1)*H_{n-2}; clip Hn (n>=2)
        // to [-100,100] BEFORE it feeds the next recursion step (matches ref).
        float hm2 = 1.0f;
        float hm1 = 2.0f * xs;
        acc[0] += g;
        acc[1] += hm1 * g;
#pragma unroll
        for (int n = 2; n <= 6; ++n) {
            float hn = 2.0f * xs * hm1 - 2.0f * (float)(n - 1) * hm2;
            hn = fminf(fmaxf(hn, -100.0f), 100.0f);
            acc[n] += hn * g;
            hm2 = hm1;
            hm1 = hn;
        }
    }

    // Wave64 butterfly reduce, then cross-wave combine in LDS.
#pragma unroll
    for (int w = 0; w < W_DIM; ++w) {
        float a = acc[w];
#pragma unroll
        for (int off = 32; off > 0; off >>= 1)
            a += __shfl_down(a, off, 64);
        acc[w] = a;
    }
    const int wave = tid >> 6;
    if ((tid & 63) == 0) {
#pragma unroll
        for (int w = 0; w < W_DIM; ++w) s_part[wave][w] = acc[w];
    }
    __syncthreads();
    if (tid < W_DIM) {
        basis[(size_t)b * W_DIM + tid] =
            s_part[0][tid] + s_part[1][tid] + s_part[2][tid] + s_part[3][tid];
    }
}

// ---------------------------------------------------------------------------
// K2: out[b][o] = sum_w basis[b][w] * coeffs[o][w]
// One block per RB rows. Coeffs staged once per block, TRANSPOSED to [w][o]
// so each thread's 7 LDS reads are conflict-free ds_read_b128.
// Each thread owns o-columns [4*tid, 4*tid+3] -> one float4 store per row.
// ---------------------------------------------------------------------------
__global__ __launch_bounds__(BLOCK) void hermite_out(
    const float* __restrict__ basis,   // (B, W_DIM)
    const float* __restrict__ coeffs,  // (O_DIM, W_DIM)
    float* __restrict__ out)           // (B, O_DIM)
{
    __shared__ float s_c[W_DIM][O_DIM];      // 28 KiB, transposed coeffs
    __shared__ float s_b[RB][W_DIM + 1];

    const int tid = threadIdx.x;
    const int b0  = blockIdx.x * RB;

    // Stage coeffs transposed: global read coalesced, LDS write scattered
    // (28 writes/thread, once per block -- cheap at 512 blocks).
    for (int i = tid; i < O_DIM * W_DIM; i += BLOCK) {
        const int o = i / W_DIM;
        const int w = i - o * W_DIM;
        s_c[w][o] = coeffs[i];
    }
    if (tid < RB * W_DIM) {
        const int r = tid / W_DIM;
        const int w = tid - r * W_DIM;
        s_b[r][w] = basis[(size_t)(b0 + r) * W_DIM + w];
    }
    __syncthreads();

    // Each thread's coeff fragment: 7 x float4, conflict-free b128 reads.
    float4 c[W_DIM];
#pragma unroll
    for (int w = 0; w < W_DIM; ++w)
        c[w] = *(const float4*)&s_c[w][tid * 4];

#pragma unroll
    for (int r = 0; r < RB; ++r) {
        float4 a;
        const float b0w = s_b[r][0];
        a.x = b0w * c[0].x; a.y = b0w * c[0].y;
        a.z = b0w * c[0].z; a.w = b0w * c[0].w;
#pragma unroll
        for (int w = 1; w < W_DIM; ++w) {
            const float bw = s_b[r][w];   // broadcast, no conflict
            a.x = fmaf(bw, c[w].x, a.x);
            a.y = fmaf(bw, c[w].y, a.y);
            a.z = fmaf(bw, c[w].z, a.z);
            a.w = fmaf(bw, c[w].w, a.w);
        }
        ((float4*)(out + (size_t)(b0 + r) * O_DIM))[tid] = a;
    }
}

extern "C" void kernel_launch(void* const* d_in, const int* in_sizes, int n_in,
                              void* d_out, int out_size, void* d_ws, size_t ws_size,
                              hipStream_t stream) {
    const float* x      = (const float*)d_in[0];  // (B, F) fp32
    const float* coeffs = (const float*)d_in[1];  // (O, W) fp32
    const float* sigma  = (const float*)d_in[2];  // (1,)   fp32
    float* out          = (float*)d_out;          // (B, O) fp32
    float* basis        = (float*)d_ws;           // (B, W) scratch

    const int B = in_sizes[0] / F_DIM;

    hermite_basis<<<dim3(B), dim3(BLOCK), 0, stream>>>(x, sigma, basis);
    hermite_out<<<dim3(B / RB), dim3(BLOCK), 0, stream>>>(basis, coeffs, out);
}

// Round 3
// 77.957 us; speedup vs baseline: 1.0975x; 1.0509x over previous
//
#include <hip/hip_runtime.h>

// Problem constants (fixed by the reference setup_inputs()).
#define F_DIM   1024   // in_features
#define O_DIM   1024   // out_features
#define W_DIM   7      // DEGREE - START_DEGREE + 1
#define BLOCK   256
#define RB      8      // rows per block (2 rows per wave, 4 waves)

// Fused single-launch kernel. Block = 8 batch rows:
//   - stage coeffs TRANSPOSED [w][o] into LDS once per block (512 blocks)
//   - each wave owns 2 rows: 64 lanes x 16 elems (4 strided float4 loads),
//     Hermite recursion * gaussian, 6-stage xor-butterfly reduce per basis w
//   - one barrier, then each thread emits out[b][4t..4t+3] for all 8 rows
//     from conflict-free ds_read_b128 coeff fragments.
__global__ __launch_bounds__(BLOCK) void hermite_fused(
    const float* __restrict__ x,       // (B, F)
    const float* __restrict__ coeffs,  // (O, W)
    const float* __restrict__ sigma,   // (1,)
    float* __restrict__ out)           // (B, O)
{
    __shared__ float s_c[W_DIM][O_DIM];     // 28 KiB transposed coeffs
    __shared__ float s_b[RB][W_DIM + 1];    // per-row basis

    const int tid  = threadIdx.x;
    const int lane = tid & 63;
    const int wave = tid >> 6;
    const int b0   = blockIdx.x * RB;

    // ---- stage coeffs transposed (global coalesced, 28 scalar LDS writes) ----
    for (int i = tid; i < O_DIM * W_DIM; i += BLOCK) {
        const int o = i / W_DIM;
        const int w = i - o * W_DIM;
        s_c[w][o] = coeffs[i];
    }

    const float s     = fminf(fmaxf(sigma[0], 0.1f), 5.0f);
    const float inv_s = 1.0f / s;

    // ---- per-wave: 2 rows, 16 elems/lane each ----
#pragma unroll
    for (int rr = 0; rr < 2; ++rr) {
        const int r   = wave * 2 + rr;         // local row 0..7
        const int row = b0 + r;
        const float4* xrow = (const float4*)(x + (size_t)row * F_DIM);

        // 4 independent coalesced loads (lane-contiguous, 64-float4 stride)
        float4 v[4];
        v[0] = xrow[lane];
        v[1] = xrow[lane + 64];
        v[2] = xrow[lane + 128];
        v[3] = xrow[lane + 192];

        float acc[W_DIM];
#pragma unroll
        for (int w = 0; w < W_DIM; ++w) acc[w] = 0.0f;

#pragma unroll
        for (int q = 0; q < 4; ++q) {
            const float el[4] = {v[q].x, v[q].y, v[q].z, v[q].w};
#pragma unroll
            for (int e = 0; e < 4; ++e) {
                const float xs = el[e] * inv_s;
                const float g  = __expf(-fminf(xs * xs, 50.0f));
                // H0=1, H1=2x, Hn = 2x*H_{n-1} - 2(n-1)*H_{n-2}; clip Hn
                // (n>=2) to [-100,100] before it feeds the next step (ref).
                float hm2 = 1.0f;
                float hm1 = 2.0f * xs;
                acc[0] += g;
                acc[1] += hm1 * g;
#pragma unroll
                for (int n = 2; n <= 6; ++n) {
                    float hn = 2.0f * xs * hm1 - 2.0f * (float)(n - 1) * hm2;
                    hn = fminf(fmaxf(hn, -100.0f), 100.0f);
                    acc[n] += hn * g;
                    hm2 = hm1;
                    hm1 = hn;
                }
            }
        }

        // xor-butterfly reduce across the wave (all lanes end with the sum)
#pragma unroll
        for (int w = 0; w < W_DIM; ++w) {
            float a = acc[w];
#pragma unroll
            for (int m = 32; m > 0; m >>= 1)
                a += __shfl_xor(a, m, 64);
            if (lane == 0) s_b[r][w] = a;
        }
    }

    __syncthreads();

    // ---- epilogue: out[b0+r][4t..4t+3] = sum_w basis[r][w]*coeffs[o][w] ----
    float4 c[W_DIM];
#pragma unroll
    for (int w = 0; w < W_DIM; ++w)
        c[w] = *(const float4*)&s_c[w][tid * 4];   // conflict-free b128

#pragma unroll
    for (int r = 0; r < RB; ++r) {
        const float bw0 = s_b[r][0];               // broadcast reads
        float4 a;
        a.x = bw0 * c[0].x; a.y = bw0 * c[0].y;
        a.z = bw0 * c[0].z; a.w = bw0 * c[0].w;
#pragma unroll
        for (int w = 1; w < W_DIM; ++w) {
            const float bw = s_b[r][w];
            a.x = fmaf(bw, c[w].x, a.x);
            a.y = fmaf(bw, c[w].y, a.y);
            a.z = fmaf(bw, c[w].z, a.z);
            a.w = fmaf(bw, c[w].w, a.w);
        }
        ((float4*)(out + (size_t)(b0 + r) * O_DIM))[tid] = a;
    }
}

extern "C" void kernel_launch(void* const* d_in, const int* in_sizes, int n_in,
                              void* d_out, int out_size, void* d_ws, size_t ws_size,
                              hipStream_t stream) {
    const float* x      = (const float*)d_in[0];  // (B, F) fp32
    const float* coeffs = (const float*)d_in[1];  // (O, W) fp32
    const float* sigma  = (const float*)d_in[2];  // (1,)   fp32
    float* out          = (float*)d_out;          // (B, O) fp32

    const int B = in_sizes[0] / F_DIM;
    hermite_fused<<<dim3(B / RB), dim3(BLOCK), 0, stream>>>(x, coeffs, sigma, out);
}

// Round 4
// 77.781 us; speedup vs baseline: 1.0999x; 1.0023x over previous
//
#include <hip/hip_runtime.h>

// Problem constants (fixed by the reference setup_inputs()).
#define F_DIM   1024   // in_features
#define O_DIM   1024   // out_features
#define W_DIM   7      // DEGREE - START_DEGREE + 1
#define BLOCK   256
#define RB      8      // rows per block (2 rows per wave, 4 waves)

// Fully wave-autonomous fused kernel: no LDS, no barriers.
// Each wave owns 2 batch rows end-to-end:
//   1. 64 lanes x 16 elems/row (4 strided float4 loads), Hermite recursion
//      * gaussian, 6-stage xor-butterfly -> every lane holds basis[w] sums.
//   2. Epilogue per quarter q: lane loads its 4 output columns' coeffs as
//      7 CONTIGUOUS float4s straight from global (o*7 layout => floats
//      [28k, 28k+28) for o=4k..4k+3; L1-resident, 28 KiB), computes
//      out[row][4k..4k+3] = sum_w basis[w]*coeffs[o][w], one float4 store.
__global__ __launch_bounds__(BLOCK) void hermite_fused(
    const float* __restrict__ x,       // (B, F)
    const float* __restrict__ coeffs,  // (O, W)
    const float* __restrict__ sigma,   // (1,)
    float* __restrict__ out)           // (B, O)
{
    const int tid  = threadIdx.x;
    const int lane = tid & 63;
    const int wave = tid >> 6;
    const int r0   = blockIdx.x * RB + wave * 2;   // this wave's first row

    const float s     = fminf(fmaxf(sigma[0], 0.1f), 5.0f);
    const float inv_s = 1.0f / s;

    // ---- phase 1: basis for 2 rows, kept in registers (all lanes) ----
    float basis[2][W_DIM];

#pragma unroll
    for (int rr = 0; rr < 2; ++rr) {
        const float4* xrow = (const float4*)(x + (size_t)(r0 + rr) * F_DIM);

        float4 v[4];
        v[0] = xrow[lane];
        v[1] = xrow[lane + 64];
        v[2] = xrow[lane + 128];
        v[3] = xrow[lane + 192];

        float acc[W_DIM];
#pragma unroll
        for (int w = 0; w < W_DIM; ++w) acc[w] = 0.0f;

#pragma unroll
        for (int q = 0; q < 4; ++q) {
            const float el[4] = {v[q].x, v[q].y, v[q].z, v[q].w};
#pragma unroll
            for (int e = 0; e < 4; ++e) {
                const float xs = el[e] * inv_s;
                const float g  = __expf(-fminf(xs * xs, 50.0f));
                // H0=1, H1=2x, Hn = 2x*H_{n-1} - 2(n-1)*H_{n-2}; clip Hn
                // (n>=2) to [-100,100] before it feeds the next step (ref).
                float hm2 = 1.0f;
                float hm1 = 2.0f * xs;
                acc[0] += g;
                acc[1] += hm1 * g;
#pragma unroll
                for (int n = 2; n <= 6; ++n) {
                    float hn = 2.0f * xs * hm1 - 2.0f * (float)(n - 1) * hm2;
                    hn = fminf(fmaxf(hn, -100.0f), 100.0f);
                    acc[n] += hn * g;
                    hm2 = hm1;
                    hm1 = hn;
                }
            }
        }

        // xor-butterfly: every lane ends with the full row sum
#pragma unroll
        for (int w = 0; w < W_DIM; ++w) {
            float a = acc[w];
#pragma unroll
            for (int m = 32; m > 0; m >>= 1)
                a += __shfl_xor(a, m, 64);
            basis[rr][w] = a;
        }
    }

    // ---- phase 2: epilogue, no LDS, coeffs straight from global (L1) ----
#pragma unroll
    for (int q = 0; q < 4; ++q) {
        const int k = q * 64 + lane;          // float4 index within the row
        const float4* cp = (const float4*)(coeffs + (size_t)28 * k);
        float cf[28];
#pragma unroll
        for (int j = 0; j < 7; ++j) {
            const float4 c4 = cp[j];
            cf[4 * j + 0] = c4.x; cf[4 * j + 1] = c4.y;
            cf[4 * j + 2] = c4.z; cf[4 * j + 3] = c4.w;
        }

#pragma unroll
        for (int rr = 0; rr < 2; ++rr) {
            float4 a;
            a.x = basis[rr][0] * cf[0];
            a.y = basis[rr][0] * cf[7];
            a.z = basis[rr][0] * cf[14];
            a.w = basis[rr][0] * cf[21];
#pragma unroll
            for (int w = 1; w < W_DIM; ++w) {
                const float bw = basis[rr][w];
                a.x = fmaf(bw, cf[w],      a.x);
                a.y = fmaf(bw, cf[7 + w],  a.y);
                a.z = fmaf(bw, cf[14 + w], a.z);
                a.w = fmaf(bw, cf[21 + w], a.w);
            }
            ((float4*)(out + (size_t)(r0 + rr) * O_DIM))[k] = a;
        }
    }
}

extern "C" void kernel_launch(void* const* d_in, const int* in_sizes, int n_in,
                              void* d_out, int out_size, void* d_ws, size_t ws_size,
                              hipStream_t stream) {
    const float* x      = (const float*)d_in[0];  // (B, F) fp32
    const float* coeffs = (const float*)d_in[1];  // (O, W) fp32
    const float* sigma  = (const float*)d_in[2];  // (1,)   fp32
    float* out          = (float*)d_out;          // (B, O) fp32

    const int B = in_sizes[0] / F_DIM;
    hermite_fused<<<dim3(B / RB), dim3(BLOCK), 0, stream>>>(x, coeffs, sigma, out);
}